// Round 1
// baseline (11166.183 us; speedup 1.0000x reference)
//
#include <hip/hip_runtime.h>
#include <math.h>

#define N_NODES 50000
#define N_EDGES 800000

__device__ __forceinline__ float silu_f(float x) {
    return x * __fdividef(1.f, 1.f + __expf(-x));
}

// ---------------- K1: per-node pre (s1,v1 -> ws; sc_s,sc_v -> out) ----------
__global__ void __launch_bounds__(256) k_node_pre(
    const float* __restrict__ node_feats,
    const int*   __restrict__ specie,
    const float* __restrict__ Wus,   // 32x32
    const float* __restrict__ Wuv,   // 32x32
    const float* __restrict__ Wss,   // 5x32x32
    const float* __restrict__ Wsv,   // 5x32x32
    float* __restrict__ s1v1,        // N x 128  [s1(32), v1 m*3+c (96)]
    float* __restrict__ out)         // N x 128  gets sc
{
    int n = blockIdx.x * 256 + threadIdx.x;
    if (n >= N_NODES) return;
    int part = blockIdx.y;           // 0 = scalar part, 1..3 = vector c
    const float* nf = node_feats + (size_t)n * 128;
    float* srow = s1v1 + (size_t)n * 128;
    float* orow = out  + (size_t)n * 128;
    int sp = specie[n];
    const float RS32 = 0.17677669529663687f; // 1/sqrt(32)

    if (part == 0) {
        float s[32];
        #pragma unroll
        for (int q = 0; q < 8; ++q) {
            float4 t = *reinterpret_cast<const float4*>(nf + 4*q);
            s[4*q+0]=t.x; s[4*q+1]=t.y; s[4*q+2]=t.z; s[4*q+3]=t.w;
        }
        float acc[32];
        #pragma unroll
        for (int k = 0; k < 32; ++k) acc[k] = 0.f;
        #pragma unroll
        for (int m = 0; m < 32; ++m) {
            float sm = s[m];
            #pragma unroll
            for (int k = 0; k < 32; ++k) acc[k] += sm * Wus[m*32 + k];
        }
        #pragma unroll
        for (int k = 0; k < 32; ++k) srow[k] = acc[k] * RS32;

        const float* Wp = Wss + sp * 1024;
        #pragma unroll
        for (int k = 0; k < 32; ++k) acc[k] = 0.f;
        #pragma unroll
        for (int i = 0; i < 32; ++i) {
            float si = s[i];
            #pragma unroll
            for (int j = 0; j < 32; ++j) acc[j] += si * __ldg(Wp + i*32 + j);
        }
        #pragma unroll
        for (int j = 0; j < 32; ++j) orow[j] = acc[j] * RS32;
    } else {
        int c = part - 1;
        float v[32];
        #pragma unroll
        for (int m = 0; m < 32; ++m) v[m] = nf[32 + m*3 + c];
        float acc[32];
        #pragma unroll
        for (int k = 0; k < 32; ++k) acc[k] = 0.f;
        #pragma unroll
        for (int m = 0; m < 32; ++m) {
            float vm = v[m];
            #pragma unroll
            for (int k = 0; k < 32; ++k) acc[k] += vm * Wuv[m*32 + k];
        }
        #pragma unroll
        for (int k = 0; k < 32; ++k) srow[32 + k*3 + c] = acc[k] * RS32;

        const float* Wp = Wsv + sp * 1024;
        #pragma unroll
        for (int k = 0; k < 32; ++k) acc[k] = 0.f;
        #pragma unroll
        for (int m = 0; m < 32; ++m) {
            float vm = v[m];
            #pragma unroll
            for (int k = 0; k < 32; ++k) acc[k] += vm * __ldg(Wp + m*32 + k);
        }
        #pragma unroll
        for (int k = 0; k < 32; ++k) orow[32 + k*3 + c] = acc[k] * RS32;
    }
}

// ---------------- K2: per-edge (radial, MLP, messages, atomic scatter) ------
__global__ void __launch_bounds__(64) k_edge(
    const float* __restrict__ vectors,
    const int*   __restrict__ senders,
    const int*   __restrict__ receivers,
    const float* __restrict__ W1,    // 8x64
    const float* __restrict__ W2,    // 64x64
    const float* __restrict__ W3,    // 64x64
    const float* __restrict__ W4,    // 64x128
    const float* __restrict__ s1v1,  // N x 128
    float* __restrict__ agg)         // N x 256  [s(64), v m*3+c (192)]
{
    int e = blockIdx.x * 64 + threadIdx.x;
    if (e >= N_EDGES) return;

    float vx = vectors[3*e+0], vy = vectors[3*e+1], vz = vectors[3*e+2];
    float x2 = vx*vx + vy*vy + vz*vz;
    float len = sqrtf(x2 == 0.f ? 1.f : x2);
    float invl = 1.f / len;
    float l2 = len*len, l3 = l2*len, l6 = l3*l3;
    float env = (len < 1.f) ? (1.f - 28.f*l6 + 48.f*l6*len - 21.f*l6*l2) : 0.f;

    const float SQRT2 = 1.4142135623730951f;
    const float PI    = 3.14159265358979f;
    float radial[8];
    #pragma unroll
    for (int nb = 0; nb < 8; ++nb)
        radial[nb] = SQRT2 * __sinf(PI * (float)(nb+1) * len) * invl * env;

    const float SQ3 = 1.7320508075688772f;
    float shx = SQ3 * vx * invl;
    float shy = SQ3 * vy * invl;
    float shz = SQ3 * vz * invl;

    const float RS8  = 0.35355339059327373f;  // 1/sqrt(8)
    const float RS64 = 0.125f;                // 1/sqrt(64)
    const float RS3  = 0.5773502691896258f;   // 1/sqrt(3)

    float A[64], B[64];

    // layer 1 -> A (h1)
    #pragma unroll
    for (int j = 0; j < 64; ++j) A[j] = 0.f;
    #pragma unroll
    for (int i = 0; i < 8; ++i) {
        float hi = radial[i];
        #pragma unroll
        for (int j = 0; j < 64; ++j) A[j] += hi * W1[i*64 + j];
    }
    #pragma unroll
    for (int j = 0; j < 64; ++j) A[j] = silu_f(A[j] * RS8);

    // layer 2 -> B (h2)
    #pragma unroll
    for (int j = 0; j < 64; ++j) B[j] = 0.f;
    #pragma unroll
    for (int i = 0; i < 64; ++i) {
        float hi = A[i];
        #pragma unroll
        for (int j = 0; j < 64; ++j) B[j] += hi * W2[i*64 + j];
    }
    #pragma unroll
    for (int j = 0; j < 64; ++j) B[j] = silu_f(B[j] * RS64);

    // layer 3 -> A (h3); h1 dead
    #pragma unroll
    for (int j = 0; j < 64; ++j) A[j] = 0.f;
    #pragma unroll
    for (int i = 0; i < 64; ++i) {
        float hi = B[i];
        #pragma unroll
        for (int j = 0; j < 64; ++j) A[j] += hi * W3[i*64 + j];
    }
    #pragma unroll
    for (int j = 0; j < 64; ++j) A[j] = silu_f(A[j] * RS64);

    // mix2 (v-part of mix, cols 64..128) -> B; h2 dead
    #pragma unroll
    for (int j = 0; j < 64; ++j) B[j] = 0.f;
    #pragma unroll
    for (int i = 0; i < 64; ++i) {
        float hi = A[i];
        #pragma unroll
        for (int j = 0; j < 64; ++j) B[j] += hi * W4[i*128 + 64 + j];
    }
    #pragma unroll
    for (int j = 0; j < 64; ++j) B[j] *= RS64;

    int snd = senders[e];
    int rcv = receivers[e];
    const float* srow = s1v1 + (size_t)snd * 128;
    float* arow = agg + (size_t)rcv * 256;

    // ms -> C
    float C[32];
    #pragma unroll
    for (int q = 0; q < 8; ++q) {
        float4 t = *reinterpret_cast<const float4*>(srow + 4*q);
        C[4*q+0]=t.x; C[4*q+1]=t.y; C[4*q+2]=t.z; C[4*q+3]=t.w;
    }

    // tp_v rows (message v rows 32..64): ms[m]*sh*mix2[32+m]
    #pragma unroll
    for (int m = 0; m < 32; ++m) {
        float f = C[m] * B[32+m];
        atomicAdd(arow + 64 + (32+m)*3 + 0, f*shx);
        atomicAdd(arow + 64 + (32+m)*3 + 1, f*shy);
        atomicAdd(arow + 64 + (32+m)*3 + 2, f*shz);
    }

    // mv rows (message v rows 0..32) + accumulate tp_s into D
    float D[32];
    #pragma unroll
    for (int b = 0; b < 4; ++b) {
        float bat[24];
        #pragma unroll
        for (int q = 0; q < 6; ++q) {
            float4 t = *reinterpret_cast<const float4*>(srow + 32 + b*24 + 4*q);
            bat[4*q+0]=t.x; bat[4*q+1]=t.y; bat[4*q+2]=t.z; bat[4*q+3]=t.w;
        }
        #pragma unroll
        for (int mm = 0; mm < 8; ++mm) {
            int m = b*8 + mm;
            float mvx = bat[3*mm+0], mvy = bat[3*mm+1], mvz = bat[3*mm+2];
            D[m] = (mvx*shx + mvy*shy + mvz*shz) * RS3;
            float f = B[m];
            atomicAdd(arow + 64 + m*3 + 0, mvx*f);
            atomicAdd(arow + 64 + m*3 + 1, mvy*f);
            atomicAdd(arow + 64 + m*3 + 2, mvz*f);
        }
    }

    // mix_s (cols 0..64) -> B; mix2 dead
    #pragma unroll
    for (int j = 0; j < 64; ++j) B[j] = 0.f;
    #pragma unroll
    for (int i = 0; i < 64; ++i) {
        float hi = A[i];
        #pragma unroll
        for (int j = 0; j < 64; ++j) B[j] += hi * W4[i*128 + j];
    }
    #pragma unroll
    for (int j = 0; j < 64; ++j) B[j] *= RS64;

    // scalar message: [ms(32), tp_s(32)] * mix_s
    #pragma unroll
    for (int j = 0; j < 32; ++j) atomicAdd(arow + j,      C[j] * B[j]);
    #pragma unroll
    for (int j = 0; j < 32; ++j) atomicAdd(arow + 32 + j, D[j] * B[32+j]);
}

// ---------------- K3: per-node post (down-proj, gating, += into out) --------
__global__ void __launch_bounds__(256) k_node_post(
    const float* __restrict__ agg,   // N x 256
    const float* __restrict__ Wds,   // 64x64
    const float* __restrict__ Wdv,   // 64x32
    float* __restrict__ out)         // N x 128 (holds sc from K1)
{
    int n = blockIdx.x * 256 + threadIdx.x;
    if (n >= N_NODES) return;
    int part = blockIdx.y;           // 0 = scalar, 1..3 = vector c
    const float* arow = agg + (size_t)n * 256;
    float* orow = out + (size_t)n * 128;
    const float SC = 0.03125f;       // (1/sqrt(16)) * (1/sqrt(64)) = 0.25*0.125

    float as[64];
    #pragma unroll
    for (int q = 0; q < 16; ++q) {
        float4 t = *reinterpret_cast<const float4*>(arow + 4*q);
        as[4*q+0]=t.x; as[4*q+1]=t.y; as[4*q+2]=t.z; as[4*q+3]=t.w;
    }

    if (part == 0) {
        float acc[32];
        #pragma unroll
        for (int k = 0; k < 32; ++k) acc[k] = 0.f;
        #pragma unroll
        for (int m = 0; m < 64; ++m) {
            float am = as[m];
            #pragma unroll
            for (int k = 0; k < 32; ++k) acc[k] += am * Wds[m*64 + k];
        }
        #pragma unroll
        for (int k = 0; k < 32; ++k) orow[k] += silu_f(acc[k] * SC);
    } else {
        int c = part - 1;
        // g = silu(d_s upper half)
        float acc[32];
        #pragma unroll
        for (int k = 0; k < 32; ++k) acc[k] = 0.f;
        #pragma unroll
        for (int m = 0; m < 64; ++m) {
            float am = as[m];
            #pragma unroll
            for (int k = 0; k < 32; ++k) acc[k] += am * Wds[m*64 + 32 + k];
        }
        float g[32];
        #pragma unroll
        for (int k = 0; k < 32; ++k) g[k] = silu_f(acc[k] * SC);

        float av[64];
        #pragma unroll
        for (int m = 0; m < 64; ++m) av[m] = arow[64 + m*3 + c];
        #pragma unroll
        for (int k = 0; k < 32; ++k) acc[k] = 0.f;
        #pragma unroll
        for (int m = 0; m < 64; ++m) {
            float am = av[m];
            #pragma unroll
            for (int k = 0; k < 32; ++k) acc[k] += am * Wdv[m*32 + k];
        }
        #pragma unroll
        for (int k = 0; k < 32; ++k) orow[32 + k*3 + c] += acc[k] * SC * g[k];
    }
}

extern "C" void kernel_launch(void* const* d_in, const int* in_sizes, int n_in,
                              void* d_out, int out_size, void* d_ws, size_t ws_size,
                              hipStream_t stream) {
    const float* vectors    = (const float*)d_in[0];
    const float* node_feats = (const float*)d_in[1];
    const float* W_skip_s   = (const float*)d_in[2];
    const float* W_skip_v   = (const float*)d_in[3];
    const float* W_up_s     = (const float*)d_in[4];
    const float* W_up_v     = (const float*)d_in[5];
    const float* W_mlp1     = (const float*)d_in[6];
    const float* W_mlp2     = (const float*)d_in[7];
    const float* W_mlp3     = (const float*)d_in[8];
    const float* W_mlp4     = (const float*)d_in[9];
    const float* W_down_s   = (const float*)d_in[10];
    const float* W_down_v   = (const float*)d_in[11];
    const int*   node_specie= (const int*)d_in[12];
    const int*   senders    = (const int*)d_in[13];
    const int*   receivers  = (const int*)d_in[14];
    float* out = (float*)d_out;

    float* s1v1 = (float*)d_ws;                       // N*128 floats
    float* agg  = s1v1 + (size_t)N_NODES * 128;       // N*256 floats

    hipMemsetAsync(agg, 0, (size_t)N_NODES * 256 * sizeof(float), stream);

    dim3 gn((N_NODES + 255) / 256, 4);
    k_node_pre<<<gn, 256, 0, stream>>>(node_feats, node_specie, W_up_s, W_up_v,
                                       W_skip_s, W_skip_v, s1v1, out);
    k_edge<<<dim3(N_EDGES / 64), 64, 0, stream>>>(vectors, senders, receivers,
                                                  W_mlp1, W_mlp2, W_mlp3, W_mlp4,
                                                  s1v1, agg);
    k_node_post<<<gn, 256, 0, stream>>>(agg, W_down_s, W_down_v, out);
}

// Round 2
// 5495.594 us; speedup vs baseline: 2.0318x; 2.0318x over previous
//
#include <hip/hip_runtime.h>
#include <math.h>

#define N_NODES 50000
#define N_EDGES 800000
// padded slot capacity: E + 15*N rounded up to grid of 256-thread blocks
#define EDGE_BLOCKS 6055
#define MAX_SLOTS (EDGE_BLOCKS * 256)        // 1,550,080 >= 800000 + 15*50000
#define MAX_GROUPS (MAX_SLOTS / 16)          // 96,880

__device__ __forceinline__ float silu_f(float x) {
    return x * __fdividef(1.f, 1.f + __expf(-x));
}

// sum across each aligned 16-lane group; result valid at lane (id%16)==15
__device__ __forceinline__ float grp16_sum(float x) {
    int v;
    v = __builtin_amdgcn_update_dpp(0, __float_as_int(x), 0x111, 0xf, 0xf, true);
    x += __int_as_float(v);
    v = __builtin_amdgcn_update_dpp(0, __float_as_int(x), 0x112, 0xf, 0xf, true);
    x += __int_as_float(v);
    v = __builtin_amdgcn_update_dpp(0, __float_as_int(x), 0x114, 0xf, 0xf, true);
    x += __int_as_float(v);
    v = __builtin_amdgcn_update_dpp(0, __float_as_int(x), 0x118, 0xf, 0xf, true);
    x += __int_as_float(v);
    return x;
}

// ---------------- K1: per-node pre (s1,v1 -> ws; sc_s,sc_v -> out) ----------
__global__ void __launch_bounds__(256) k_node_pre(
    const float* __restrict__ node_feats,
    const int*   __restrict__ specie,
    const float* __restrict__ Wus,   // 32x32
    const float* __restrict__ Wuv,   // 32x32
    const float* __restrict__ Wss,   // 5x32x32
    const float* __restrict__ Wsv,   // 5x32x32
    float* __restrict__ s1v1,        // N x 128  [s1(32), v1 m*3+c (96)]
    float* __restrict__ out)         // N x 128  gets sc
{
    int n = blockIdx.x * 256 + threadIdx.x;
    if (n >= N_NODES) return;
    int part = blockIdx.y;           // 0 = scalar part, 1..3 = vector c
    const float* nf = node_feats + (size_t)n * 128;
    float* srow = s1v1 + (size_t)n * 128;
    float* orow = out  + (size_t)n * 128;
    int sp = specie[n];
    const float RS32 = 0.17677669529663687f; // 1/sqrt(32)

    if (part == 0) {
        float s[32];
        #pragma unroll
        for (int q = 0; q < 8; ++q) {
            float4 t = *reinterpret_cast<const float4*>(nf + 4*q);
            s[4*q+0]=t.x; s[4*q+1]=t.y; s[4*q+2]=t.z; s[4*q+3]=t.w;
        }
        float acc[32];
        #pragma unroll
        for (int k = 0; k < 32; ++k) acc[k] = 0.f;
        #pragma unroll
        for (int m = 0; m < 32; ++m) {
            float sm = s[m];
            #pragma unroll
            for (int k = 0; k < 32; ++k) acc[k] += sm * Wus[m*32 + k];
        }
        #pragma unroll
        for (int k = 0; k < 32; ++k) srow[k] = acc[k] * RS32;

        const float* Wp = Wss + sp * 1024;
        #pragma unroll
        for (int k = 0; k < 32; ++k) acc[k] = 0.f;
        #pragma unroll
        for (int i = 0; i < 32; ++i) {
            float si = s[i];
            #pragma unroll
            for (int j = 0; j < 32; ++j) acc[j] += si * __ldg(Wp + i*32 + j);
        }
        #pragma unroll
        for (int j = 0; j < 32; ++j) orow[j] = acc[j] * RS32;
    } else {
        int c = part - 1;
        float v[32];
        #pragma unroll
        for (int m = 0; m < 32; ++m) v[m] = nf[32 + m*3 + c];
        float acc[32];
        #pragma unroll
        for (int k = 0; k < 32; ++k) acc[k] = 0.f;
        #pragma unroll
        for (int m = 0; m < 32; ++m) {
            float vm = v[m];
            #pragma unroll
            for (int k = 0; k < 32; ++k) acc[k] += vm * Wuv[m*32 + k];
        }
        #pragma unroll
        for (int k = 0; k < 32; ++k) srow[32 + k*3 + c] = acc[k] * RS32;

        const float* Wp = Wsv + sp * 1024;
        #pragma unroll
        for (int k = 0; k < 32; ++k) acc[k] = 0.f;
        #pragma unroll
        for (int m = 0; m < 32; ++m) {
            float vm = v[m];
            #pragma unroll
            for (int k = 0; k < 32; ++k) acc[k] += vm * __ldg(Wp + m*32 + k);
        }
        #pragma unroll
        for (int k = 0; k < 32; ++k) orow[32 + k*3 + c] = acc[k] * RS32;
    }
}

// ---------------- sort stage: histogram -> padded scan -> scatter -----------
__global__ void __launch_bounds__(256) k_hist(
    const int* __restrict__ receivers, int* __restrict__ cnt)
{
    int e = blockIdx.x * 256 + threadIdx.x;   // grid exact: 3125*256 = 800000
    atomicAdd(&cnt[receivers[e]], 1);
}

__global__ void __launch_bounds__(1024) k_scan(
    const int* __restrict__ cnt, int* __restrict__ paddedOff, int* __restrict__ cursor)
{
    __shared__ int lds[1024];
    __shared__ int base_s;
    int t = threadIdx.x;
    if (t == 0) base_s = 0;
    __syncthreads();
    for (int start = 0; start < N_NODES; start += 1024) {
        int i = start + t;
        int c = (i < N_NODES) ? (((cnt[i] + 15) >> 4) << 4) : 0;
        lds[t] = c;
        __syncthreads();
        for (int d = 1; d < 1024; d <<= 1) {
            int v = (t >= d) ? lds[t - d] : 0;
            __syncthreads();
            lds[t] += v;
            __syncthreads();
        }
        int excl = base_s + lds[t] - c;
        if (i < N_NODES) { paddedOff[i] = excl; cursor[i] = 0; }
        __syncthreads();
        if (t == 0) base_s += lds[1023];
        __syncthreads();
    }
    if (t == 0) paddedOff[N_NODES] = base_s;
}

__global__ void __launch_bounds__(256) k_scatter(
    const float* __restrict__ vectors, const int* __restrict__ senders,
    const int* __restrict__ receivers, const int* __restrict__ paddedOff,
    int* __restrict__ cursor, float4* __restrict__ sortedVS)
{
    int e = blockIdx.x * 256 + threadIdx.x;   // grid exact
    int r = receivers[e];
    int pos = paddedOff[r] + atomicAdd(&cursor[r], 1);
    float4 vs;
    vs.x = vectors[3*e+0]; vs.y = vectors[3*e+1]; vs.z = vectors[3*e+2];
    vs.w = __int_as_float(senders[e]);
    sortedVS[pos] = vs;
}

// ---------------- K2: per-slot edge kernel, group-reduced partials ----------
__global__ void __launch_bounds__(256) k_edge_grp(
    const float4* __restrict__ sortedVS,
    const float* __restrict__ W1,    // 8x64
    const float* __restrict__ W2,    // 64x64
    const float* __restrict__ W3,    // 64x64
    const float* __restrict__ W4,    // 64x128
    const float* __restrict__ s1v1,  // N x 128
    float* __restrict__ partials)    // MAX_GROUPS x 256 [s(64), v m*3+c (192)]
{
    int i = blockIdx.x * 256 + threadIdx.x;
    float4 vs = sortedVS[i];
    bool zero = (vs.x == 0.f) && (vs.y == 0.f) && (vs.z == 0.f) && (vs.w == 0.f);
    if (__all(zero)) return;     // skip fully-dummy waves (padding tail)

    float vx = vs.x, vy = vs.y, vz = vs.z;
    int snd = __float_as_int(vs.w);

    float x2 = vx*vx + vy*vy + vz*vz;
    float len = sqrtf(x2 == 0.f ? 1.f : x2);
    float invl = 1.f / len;
    float l2 = len*len, l3 = l2*len, l6 = l3*l3;
    float env = (len < 1.f) ? (1.f - 28.f*l6 + 48.f*l6*len - 21.f*l6*l2) : 0.f;

    const float SQRT2 = 1.4142135623730951f;
    const float PI    = 3.14159265358979f;
    float radial[8];
    #pragma unroll
    for (int nb = 0; nb < 8; ++nb)
        radial[nb] = SQRT2 * __sinf(PI * (float)(nb+1) * len) * invl * env;

    const float SQ3 = 1.7320508075688772f;
    float shx = SQ3 * vx * invl;
    float shy = SQ3 * vy * invl;
    float shz = SQ3 * vz * invl;

    const float RS8  = 0.35355339059327373f;  // 1/sqrt(8)
    const float RS64 = 0.125f;                // 1/sqrt(64)
    const float RS3  = 0.5773502691896258f;   // 1/sqrt(3)

    float A[64], B[64];

    // layer 1 -> A (h1)
    #pragma unroll
    for (int j = 0; j < 64; ++j) A[j] = 0.f;
    #pragma unroll
    for (int i2 = 0; i2 < 8; ++i2) {
        float hi = radial[i2];
        #pragma unroll
        for (int j = 0; j < 64; ++j) A[j] += hi * W1[i2*64 + j];
    }
    #pragma unroll
    for (int j = 0; j < 64; ++j) A[j] = silu_f(A[j] * RS8);

    // layer 2 -> B (h2)
    #pragma unroll
    for (int j = 0; j < 64; ++j) B[j] = 0.f;
    #pragma unroll
    for (int i2 = 0; i2 < 64; ++i2) {
        float hi = A[i2];
        #pragma unroll
        for (int j = 0; j < 64; ++j) B[j] += hi * W2[i2*64 + j];
    }
    #pragma unroll
    for (int j = 0; j < 64; ++j) B[j] = silu_f(B[j] * RS64);

    // layer 3 -> A (h3)
    #pragma unroll
    for (int j = 0; j < 64; ++j) A[j] = 0.f;
    #pragma unroll
    for (int i2 = 0; i2 < 64; ++i2) {
        float hi = B[i2];
        #pragma unroll
        for (int j = 0; j < 64; ++j) A[j] += hi * W3[i2*64 + j];
    }
    #pragma unroll
    for (int j = 0; j < 64; ++j) A[j] = silu_f(A[j] * RS64);

    // mix_v (cols 64..128) -> B
    #pragma unroll
    for (int j = 0; j < 64; ++j) B[j] = 0.f;
    #pragma unroll
    for (int i2 = 0; i2 < 64; ++i2) {
        float hi = A[i2];
        #pragma unroll
        for (int j = 0; j < 64; ++j) B[j] += hi * W4[i2*128 + 64 + j];
    }
    #pragma unroll
    for (int j = 0; j < 64; ++j) B[j] *= RS64;

    const float* srow = s1v1 + (size_t)snd * 128;
    float* prow = partials + ((size_t)(i >> 4)) * 256;
    bool leader = ((threadIdx.x & 15) == 15);

    // ms -> C
    float C[32];
    #pragma unroll
    for (int q = 0; q < 8; ++q) {
        float4 t = *reinterpret_cast<const float4*>(srow + 4*q);
        C[4*q+0]=t.x; C[4*q+1]=t.y; C[4*q+2]=t.z; C[4*q+3]=t.w;
    }

    // tp_v rows (v rows 32..63): comps at 160 + 3m + c
    #pragma unroll
    for (int m = 0; m < 32; ++m) {
        float f = C[m] * B[32+m];
        float sx = grp16_sum(f*shx);
        float sy = grp16_sum(f*shy);
        float sz = grp16_sum(f*shz);
        if (leader) {
            prow[160 + 3*m + 0] = sx;
            prow[160 + 3*m + 1] = sy;
            prow[160 + 3*m + 2] = sz;
        }
    }

    // mv rows (v rows 0..31): comps at 64 + 3m + c; also tp_s -> D
    float D[32];
    #pragma unroll
    for (int b = 0; b < 4; ++b) {
        float bat[24];
        #pragma unroll
        for (int q = 0; q < 6; ++q) {
            float4 t = *reinterpret_cast<const float4*>(srow + 32 + b*24 + 4*q);
            bat[4*q+0]=t.x; bat[4*q+1]=t.y; bat[4*q+2]=t.z; bat[4*q+3]=t.w;
        }
        #pragma unroll
        for (int mm = 0; mm < 8; ++mm) {
            int m = b*8 + mm;
            float mvx = bat[3*mm+0], mvy = bat[3*mm+1], mvz = bat[3*mm+2];
            D[m] = (mvx*shx + mvy*shy + mvz*shz) * RS3;
            float f = B[m];
            float sx = grp16_sum(mvx*f);
            float sy = grp16_sum(mvy*f);
            float sz = grp16_sum(mvz*f);
            if (leader) {
                prow[64 + 3*m + 0] = sx;
                prow[64 + 3*m + 1] = sy;
                prow[64 + 3*m + 2] = sz;
            }
        }
    }

    // mix_s (cols 0..64) -> B
    #pragma unroll
    for (int j = 0; j < 64; ++j) B[j] = 0.f;
    #pragma unroll
    for (int i2 = 0; i2 < 64; ++i2) {
        float hi = A[i2];
        #pragma unroll
        for (int j = 0; j < 64; ++j) B[j] += hi * W4[i2*128 + j];
    }
    #pragma unroll
    for (int j = 0; j < 64; ++j) B[j] *= RS64;

    // scalar message: [ms*mix_s (0..31), tp_s*mix_s (32..63)]
    #pragma unroll
    for (int j = 0; j < 32; ++j) {
        float s0 = grp16_sum(C[j] * B[j]);
        if (leader) prow[j] = s0;
    }
    #pragma unroll
    for (int j = 0; j < 32; ++j) {
        float s1 = grp16_sum(D[j] * B[32+j]);
        if (leader) prow[32 + j] = s1;
    }
}

// ---------------- K3: per-node post (sum partials, down-proj, gate) ---------
__global__ void __launch_bounds__(256) k_node_post(
    const float* __restrict__ partials,
    const int*   __restrict__ paddedOff,
    const float* __restrict__ Wds,   // 64x64
    const float* __restrict__ Wdv,   // 64x32
    float* __restrict__ out)         // N x 128 (holds sc from K1)
{
    int n = blockIdx.x;
    int t = threadIdx.x;
    __shared__ float agg[256];
    __shared__ float gl[32];

    int p0 = paddedOff[n]   >> 4;
    int p1 = paddedOff[n+1] >> 4;
    float a = 0.f;
    for (int g = p0; g < p1; ++g) a += partials[(size_t)g * 256 + t];
    agg[t] = a;
    __syncthreads();

    const float SC = 0.03125f;       // (1/sqrt(16)) * (1/sqrt(64))
    float* orow = out + (size_t)n * 128;

    float dv = 0.f;
    if (t < 64) {
        float acc = 0.f;
        #pragma unroll
        for (int m = 0; m < 64; ++m) acc += agg[m] * Wds[m*64 + t];
        float sv = silu_f(acc * SC);
        if (t < 32) orow[t] += sv;       // feat + sc_s
        else        gl[t - 32] = sv;     // g
    } else if (t < 160) {
        int kc = t - 64;                 // = k*3 + c
        int k = kc / 3, c = kc - 3*k;
        float acc = 0.f;
        #pragma unroll
        for (int m = 0; m < 64; ++m) acc += agg[64 + m*3 + c] * Wdv[m*32 + k];
        dv = acc * SC;
    }
    __syncthreads();
    if (t >= 64 && t < 160) {
        int kc = t - 64;
        int k = kc / 3;
        orow[32 + kc] += dv * gl[k];     // gv + sc_v
    }
}

extern "C" void kernel_launch(void* const* d_in, const int* in_sizes, int n_in,
                              void* d_out, int out_size, void* d_ws, size_t ws_size,
                              hipStream_t stream) {
    const float* vectors    = (const float*)d_in[0];
    const float* node_feats = (const float*)d_in[1];
    const float* W_skip_s   = (const float*)d_in[2];
    const float* W_skip_v   = (const float*)d_in[3];
    const float* W_up_s     = (const float*)d_in[4];
    const float* W_up_v     = (const float*)d_in[5];
    const float* W_mlp1     = (const float*)d_in[6];
    const float* W_mlp2     = (const float*)d_in[7];
    const float* W_mlp3     = (const float*)d_in[8];
    const float* W_mlp4     = (const float*)d_in[9];
    const float* W_down_s   = (const float*)d_in[10];
    const float* W_down_v   = (const float*)d_in[11];
    const int*   node_specie= (const int*)d_in[12];
    const int*   senders    = (const int*)d_in[13];
    const int*   receivers  = (const int*)d_in[14];
    float* out = (float*)d_out;

    // workspace layout (all 16B-aligned)
    float*  s1v1     = (float*)d_ws;                                  // 6.4M f
    float*  partials = s1v1 + (size_t)N_NODES * 128;                  // 24.8M f
    float4* sortedVS = (float4*)(partials + (size_t)MAX_GROUPS * 256);// 1.55M f4
    int*    cnt      = (int*)(sortedVS + MAX_SLOTS);                  // 50000
    int*    cursor   = cnt + N_NODES;                                 // 50000
    int*    paddedOff= cursor + N_NODES;                              // 50001

    hipMemsetAsync(cnt, 0, (size_t)N_NODES * sizeof(int), stream);
    hipMemsetAsync(sortedVS, 0, (size_t)MAX_SLOTS * sizeof(float4), stream);

    dim3 gn((N_NODES + 255) / 256, 4);
    k_node_pre<<<gn, 256, 0, stream>>>(node_feats, node_specie, W_up_s, W_up_v,
                                       W_skip_s, W_skip_v, s1v1, out);
    k_hist<<<N_EDGES / 256, 256, 0, stream>>>(receivers, cnt);
    k_scan<<<1, 1024, 0, stream>>>(cnt, paddedOff, cursor);
    k_scatter<<<N_EDGES / 256, 256, 0, stream>>>(vectors, senders, receivers,
                                                 paddedOff, cursor, sortedVS);
    k_edge_grp<<<EDGE_BLOCKS, 256, 0, stream>>>(sortedVS, W_mlp1, W_mlp2, W_mlp3,
                                                W_mlp4, s1v1, partials);
    k_node_post<<<N_NODES, 256, 0, stream>>>(partials, paddedOff, W_down_s,
                                             W_down_v, out);
}

// Round 3
// 3333.765 us; speedup vs baseline: 3.3494x; 1.6485x over previous
//
#include <hip/hip_runtime.h>
#include <math.h>

#define N_NODES 50000
#define N_EDGES 800000

__device__ __forceinline__ float silu_f(float x) {
    return x * __fdividef(1.f, 1.f + __expf(-x));
}

// ---------------- K1: per-node pre (s1,v1 -> ws; sc_s,sc_v -> out) ----------
__global__ void __launch_bounds__(256) k_node_pre(
    const float* __restrict__ node_feats,
    const int*   __restrict__ specie,
    const float* __restrict__ Wus,   // 32x32
    const float* __restrict__ Wuv,   // 32x32
    const float* __restrict__ Wss,   // 5x32x32
    const float* __restrict__ Wsv,   // 5x32x32
    float* __restrict__ s1v1,        // N x 128  [s1(32), v1 m*3+c (96)]
    float* __restrict__ out)         // N x 128  gets sc
{
    int n = blockIdx.x * 256 + threadIdx.x;
    if (n >= N_NODES) return;
    int part = blockIdx.y;           // 0 = scalar part, 1..3 = vector c
    const float* nf = node_feats + (size_t)n * 128;
    float* srow = s1v1 + (size_t)n * 128;
    float* orow = out  + (size_t)n * 128;
    int sp = specie[n];
    const float RS32 = 0.17677669529663687f; // 1/sqrt(32)

    if (part == 0) {
        float s[32];
        #pragma unroll
        for (int q = 0; q < 8; ++q) {
            float4 t = *reinterpret_cast<const float4*>(nf + 4*q);
            s[4*q+0]=t.x; s[4*q+1]=t.y; s[4*q+2]=t.z; s[4*q+3]=t.w;
        }
        float acc[32];
        #pragma unroll
        for (int k = 0; k < 32; ++k) acc[k] = 0.f;
        #pragma unroll
        for (int m = 0; m < 32; ++m) {
            float sm = s[m];
            #pragma unroll
            for (int k = 0; k < 32; ++k) acc[k] += sm * Wus[m*32 + k];
        }
        #pragma unroll
        for (int k = 0; k < 32; ++k) srow[k] = acc[k] * RS32;

        const float* Wp = Wss + sp * 1024;
        #pragma unroll
        for (int k = 0; k < 32; ++k) acc[k] = 0.f;
        #pragma unroll
        for (int i = 0; i < 32; ++i) {
            float si = s[i];
            #pragma unroll
            for (int j = 0; j < 32; ++j) acc[j] += si * __ldg(Wp + i*32 + j);
        }
        #pragma unroll
        for (int j = 0; j < 32; ++j) orow[j] = acc[j] * RS32;
    } else {
        int c = part - 1;
        float v[32];
        #pragma unroll
        for (int m = 0; m < 32; ++m) v[m] = nf[32 + m*3 + c];
        float acc[32];
        #pragma unroll
        for (int k = 0; k < 32; ++k) acc[k] = 0.f;
        #pragma unroll
        for (int m = 0; m < 32; ++m) {
            float vm = v[m];
            #pragma unroll
            for (int k = 0; k < 32; ++k) acc[k] += vm * Wuv[m*32 + k];
        }
        #pragma unroll
        for (int k = 0; k < 32; ++k) srow[32 + k*3 + c] = acc[k] * RS32;

        const float* Wp = Wsv + sp * 1024;
        #pragma unroll
        for (int k = 0; k < 32; ++k) acc[k] = 0.f;
        #pragma unroll
        for (int m = 0; m < 32; ++m) {
            float vm = v[m];
            #pragma unroll
            for (int k = 0; k < 32; ++k) acc[k] += vm * __ldg(Wp + m*32 + k);
        }
        #pragma unroll
        for (int k = 0; k < 32; ++k) orow[32 + k*3 + c] = acc[k] * RS32;
    }
}

// ---------------- sort stage: histogram -> scan -> scatter ------------------
__global__ void __launch_bounds__(256) k_hist(
    const int* __restrict__ receivers, int* __restrict__ cnt)
{
    int e = blockIdx.x * 256 + threadIdx.x;   // grid exact: 3125*256 = 800000
    atomicAdd(&cnt[receivers[e]], 1);
}

__global__ void __launch_bounds__(1024) k_scan(
    const int* __restrict__ cnt, int* __restrict__ off, int* __restrict__ cursor)
{
    __shared__ int lds[1024];
    __shared__ int base_s;
    int t = threadIdx.x;
    if (t == 0) base_s = 0;
    __syncthreads();
    for (int start = 0; start < N_NODES; start += 1024) {
        int i = start + t;
        int c = (i < N_NODES) ? cnt[i] : 0;
        lds[t] = c;
        __syncthreads();
        for (int d = 1; d < 1024; d <<= 1) {
            int v = (t >= d) ? lds[t - d] : 0;
            __syncthreads();
            lds[t] += v;
            __syncthreads();
        }
        int excl = base_s + lds[t] - c;
        if (i < N_NODES) { off[i] = excl; cursor[i] = 0; }
        __syncthreads();
        if (t == 0) base_s += lds[1023];
        __syncthreads();
    }
    if (t == 0) off[N_NODES] = base_s;
}

__global__ void __launch_bounds__(256) k_scatter(
    const float* __restrict__ vectors, const int* __restrict__ senders,
    const int* __restrict__ receivers, const int* __restrict__ off,
    int* __restrict__ cursor, float4* __restrict__ sortedVS)
{
    int e = blockIdx.x * 256 + threadIdx.x;   // grid exact
    int r = receivers[e];
    int pos = off[r] + atomicAdd(&cursor[r], 1);
    float4 vs;
    vs.x = vectors[3*e+0]; vs.y = vectors[3*e+1]; vs.z = vectors[3*e+2];
    vs.w = __int_as_float(senders[e]);
    sortedVS[pos] = vs;
}

// ---------------- K2: per-slot edge kernel, dense message rows --------------
__global__ void __launch_bounds__(256) k_edge(
    const float4* __restrict__ sortedVS,
    const float* __restrict__ W1,    // 8x64
    const float* __restrict__ W2,    // 64x64
    const float* __restrict__ W3,    // 64x64
    const float* __restrict__ W4,    // 64x128
    const float* __restrict__ s1v1,  // N x 128
    float* __restrict__ msgs,        // rows x 256 [s(64), v 64+3r+c]
    int r0, int r1)
{
    int slot = r0 + blockIdx.x * 256 + threadIdx.x;
    if (slot >= r1) return;
    float4 vs = sortedVS[slot];

    float vx = vs.x, vy = vs.y, vz = vs.z;
    int snd = __float_as_int(vs.w);

    float x2 = vx*vx + vy*vy + vz*vz;
    float len = sqrtf(x2 == 0.f ? 1.f : x2);
    float invl = 1.f / len;
    float l2 = len*len, l3 = l2*len, l6 = l3*l3;
    float env = (len < 1.f) ? (1.f - 28.f*l6 + 48.f*l6*len - 21.f*l6*l2) : 0.f;

    const float SQRT2 = 1.4142135623730951f;
    const float PI    = 3.14159265358979f;
    float radial[8];
    #pragma unroll
    for (int nb = 0; nb < 8; ++nb)
        radial[nb] = SQRT2 * __sinf(PI * (float)(nb+1) * len) * invl * env;

    const float SQ3 = 1.7320508075688772f;
    float shx = SQ3 * vx * invl;
    float shy = SQ3 * vy * invl;
    float shz = SQ3 * vz * invl;

    const float RS8  = 0.35355339059327373f;  // 1/sqrt(8)
    const float RS64 = 0.125f;                // 1/sqrt(64)
    const float RS3  = 0.5773502691896258f;   // 1/sqrt(3)

    float A[64], B[64];

    // layer 1 -> A (h1)
    #pragma unroll
    for (int j = 0; j < 64; ++j) A[j] = 0.f;
    #pragma unroll
    for (int i2 = 0; i2 < 8; ++i2) {
        float hi = radial[i2];
        #pragma unroll
        for (int j = 0; j < 64; ++j) A[j] += hi * W1[i2*64 + j];
    }
    #pragma unroll
    for (int j = 0; j < 64; ++j) A[j] = silu_f(A[j] * RS8);

    // layer 2 -> B (h2)
    #pragma unroll
    for (int j = 0; j < 64; ++j) B[j] = 0.f;
    #pragma unroll
    for (int i2 = 0; i2 < 64; ++i2) {
        float hi = A[i2];
        #pragma unroll
        for (int j = 0; j < 64; ++j) B[j] += hi * W2[i2*64 + j];
    }
    #pragma unroll
    for (int j = 0; j < 64; ++j) B[j] = silu_f(B[j] * RS64);

    // layer 3 -> A (h3)
    #pragma unroll
    for (int j = 0; j < 64; ++j) A[j] = 0.f;
    #pragma unroll
    for (int i2 = 0; i2 < 64; ++i2) {
        float hi = B[i2];
        #pragma unroll
        for (int j = 0; j < 64; ++j) A[j] += hi * W3[i2*64 + j];
    }
    #pragma unroll
    for (int j = 0; j < 64; ++j) A[j] = silu_f(A[j] * RS64);

    // mix_v (cols 64..128) -> B
    #pragma unroll
    for (int j = 0; j < 64; ++j) B[j] = 0.f;
    #pragma unroll
    for (int i2 = 0; i2 < 64; ++i2) {
        float hi = A[i2];
        #pragma unroll
        for (int j = 0; j < 64; ++j) B[j] += hi * W4[i2*128 + 64 + j];
    }
    #pragma unroll
    for (int j = 0; j < 64; ++j) B[j] *= RS64;

    const float* srow = s1v1 + (size_t)snd * 128;
    float* mrow = msgs + (size_t)(slot - r0) * 256;

    // ms -> C
    float C[32];
    #pragma unroll
    for (int q = 0; q < 8; ++q) {
        float4 t = *reinterpret_cast<const float4*>(srow + 4*q);
        C[4*q+0]=t.x; C[4*q+1]=t.y; C[4*q+2]=t.z; C[4*q+3]=t.w;
    }

    // tp_v rows (v rows 32..63): comps at 160 + 3m + c
    #pragma unroll
    for (int m = 0; m < 32; ++m) {
        float f = C[m] * B[32+m];
        mrow[160 + 3*m + 0] = f*shx;
        mrow[160 + 3*m + 1] = f*shy;
        mrow[160 + 3*m + 2] = f*shz;
    }

    // mv rows (v rows 0..31): comps at 64 + 3m + c; also tp_s -> D
    float D[32];
    #pragma unroll
    for (int b = 0; b < 4; ++b) {
        float bat[24];
        #pragma unroll
        for (int q = 0; q < 6; ++q) {
            float4 t = *reinterpret_cast<const float4*>(srow + 32 + b*24 + 4*q);
            bat[4*q+0]=t.x; bat[4*q+1]=t.y; bat[4*q+2]=t.z; bat[4*q+3]=t.w;
        }
        #pragma unroll
        for (int mm = 0; mm < 8; ++mm) {
            int m = b*8 + mm;
            float mvx = bat[3*mm+0], mvy = bat[3*mm+1], mvz = bat[3*mm+2];
            D[m] = (mvx*shx + mvy*shy + mvz*shz) * RS3;
            float f = B[m];
            mrow[64 + 3*m + 0] = mvx*f;
            mrow[64 + 3*m + 1] = mvy*f;
            mrow[64 + 3*m + 2] = mvz*f;
        }
    }

    // mix_s (cols 0..64) -> B
    #pragma unroll
    for (int j = 0; j < 64; ++j) B[j] = 0.f;
    #pragma unroll
    for (int i2 = 0; i2 < 64; ++i2) {
        float hi = A[i2];
        #pragma unroll
        for (int j = 0; j < 64; ++j) B[j] += hi * W4[i2*128 + j];
    }
    #pragma unroll
    for (int j = 0; j < 64; ++j) B[j] *= RS64;

    // scalar message: [ms*mix_s (0..31), tp_s*mix_s (32..63)]
    #pragma unroll
    for (int j = 0; j < 32; ++j) mrow[j]      = C[j] * B[j];
    #pragma unroll
    for (int j = 0; j < 32; ++j) mrow[32 + j] = D[j] * B[32+j];
}

// ---------------- K2b: per-node accumulate of this chunk's rows -------------
__global__ void __launch_bounds__(256) k_agg(
    const float* __restrict__ msgs,
    const int*   __restrict__ off,
    float* __restrict__ agg,         // N x 256
    int r0, int r1, int first)
{
    int n = blockIdx.x;
    int t = threadIdx.x;
    int p0 = off[n], p1 = off[n+1];
    int lo = p0 > r0 ? p0 : r0;
    int hi = p1 < r1 ? p1 : r1;
    if (!first && lo >= hi) return;
    float s = 0.f;
    for (int p = lo; p < hi; ++p) s += msgs[(size_t)(p - r0) * 256 + t];
    float* ap = agg + (size_t)n * 256 + t;
    if (first) *ap = s;
    else       *ap += s;
}

// ---------------- K3: per-node post (down-proj, gate, += into out) ----------
__global__ void __launch_bounds__(256) k_node_post(
    const float* __restrict__ agg,   // N x 256
    const float* __restrict__ Wds,   // 64x64
    const float* __restrict__ Wdv,   // 64x32
    float* __restrict__ out)         // N x 128 (holds sc from K1)
{
    int n = blockIdx.x;
    int t = threadIdx.x;
    __shared__ float a_s[256];
    __shared__ float gl[32];

    a_s[t] = agg[(size_t)n * 256 + t];
    __syncthreads();

    const float SC = 0.03125f;       // (1/sqrt(16)) * (1/sqrt(64))
    float* orow = out + (size_t)n * 128;

    float dv = 0.f;
    if (t < 64) {
        float acc = 0.f;
        #pragma unroll
        for (int m = 0; m < 64; ++m) acc += a_s[m] * Wds[m*64 + t];
        float sv = silu_f(acc * SC);
        if (t < 32) orow[t] += sv;       // feat + sc_s
        else        gl[t - 32] = sv;     // g
    } else if (t < 160) {
        int kc = t - 64;                 // = k*3 + c
        int k = kc / 3, c = kc - 3*k;
        float acc = 0.f;
        #pragma unroll
        for (int m = 0; m < 64; ++m) acc += a_s[64 + m*3 + c] * Wdv[m*32 + k];
        dv = acc * SC;
    }
    __syncthreads();
    if (t >= 64 && t < 160) {
        int kc = t - 64;
        int k = kc / 3;
        orow[32 + kc] += dv * gl[k];     // gv + sc_v
    }
}

extern "C" void kernel_launch(void* const* d_in, const int* in_sizes, int n_in,
                              void* d_out, int out_size, void* d_ws, size_t ws_size,
                              hipStream_t stream) {
    const float* vectors    = (const float*)d_in[0];
    const float* node_feats = (const float*)d_in[1];
    const float* W_skip_s   = (const float*)d_in[2];
    const float* W_skip_v   = (const float*)d_in[3];
    const float* W_up_s     = (const float*)d_in[4];
    const float* W_up_v     = (const float*)d_in[5];
    const float* W_mlp1     = (const float*)d_in[6];
    const float* W_mlp2     = (const float*)d_in[7];
    const float* W_mlp3     = (const float*)d_in[8];
    const float* W_mlp4     = (const float*)d_in[9];
    const float* W_down_s   = (const float*)d_in[10];
    const float* W_down_v   = (const float*)d_in[11];
    const int*   node_specie= (const int*)d_in[12];
    const int*   senders    = (const int*)d_in[13];
    const int*   receivers  = (const int*)d_in[14];
    float* out = (float*)d_out;

    // workspace layout
    float*  s1v1     = (float*)d_ws;                                  // N*128
    float*  agg      = s1v1 + (size_t)N_NODES * 128;                  // N*256
    float4* sortedVS = (float4*)(agg + (size_t)N_NODES * 256);        // E
    int*    cnt      = (int*)(sortedVS + N_EDGES);                    // N
    int*    cursor   = cnt + N_NODES;                                 // N
    int*    off      = cursor + N_NODES;                              // N+1
    float*  msgs     = (float*)(off + N_NODES + 2);                   // chunked

    size_t base_bytes = (size_t)((char*)msgs - (char*)d_ws);
    size_t avail = (ws_size > base_bytes + 4096) ? (ws_size - base_bytes - 4096) : 0;
    long cap = (long)(avail / 1024);            // 256 floats per row
    if (cap > N_EDGES) cap = N_EDGES;
    if (cap < 4096)    cap = 4096;              // assume ws >= ~100 MB
    int chunks = (int)((N_EDGES + cap - 1) / cap);
    int rows   = (N_EDGES + chunks - 1) / chunks;

    hipMemsetAsync(cnt, 0, (size_t)N_NODES * sizeof(int), stream);

    dim3 gn((N_NODES + 255) / 256, 4);
    k_node_pre<<<gn, 256, 0, stream>>>(node_feats, node_specie, W_up_s, W_up_v,
                                       W_skip_s, W_skip_v, s1v1, out);
    k_hist<<<N_EDGES / 256, 256, 0, stream>>>(receivers, cnt);
    k_scan<<<1, 1024, 0, stream>>>(cnt, off, cursor);
    k_scatter<<<N_EDGES / 256, 256, 0, stream>>>(vectors, senders, receivers,
                                                 off, cursor, sortedVS);
    for (int c = 0; c < chunks; ++c) {
        int r0 = c * rows;
        int r1 = r0 + rows; if (r1 > N_EDGES) r1 = N_EDGES;
        int nb = (r1 - r0 + 255) / 256;
        k_edge<<<nb, 256, 0, stream>>>(sortedVS, W_mlp1, W_mlp2, W_mlp3, W_mlp4,
                                       s1v1, msgs, r0, r1);
        k_agg<<<N_NODES, 256, 0, stream>>>(msgs, off, agg, r0, r1, (c == 0) ? 1 : 0);
    }
    k_node_post<<<N_NODES, 256, 0, stream>>>(agg, W_down_s, W_down_v, out);
}